// Round 1
// baseline (573.076 us; speedup 1.0000x reference)
//
#include <hip/hip_runtime.h>
#include <hip/hip_bf16.h>
#include <stdint.h>

// Linear-attention block: qkv proj -> (softmax_d q)*(scale), softmax_s k,
// kv = k^T v, out = q@kv, proj. Folded: MbT[b] = (kv/Z*scale) @ Wp^T so the
// final result is ONE batched GEMM: out[b] = P[b] @ MbT[b]^T + b_proj.

#define DIM 1024
#define NH 16
#define HD 64
#define BSZ 4
#define SEQ 4096
#define MTOT (BSZ*SEQ)      // 16384
#define NQKV (3*DIM)        // 3072
#define QSCALE 0.125f       // HD^-0.5

typedef __attribute__((ext_vector_type(8))) short bf16x8;
typedef __attribute__((ext_vector_type(4))) float f32x4;
typedef __attribute__((ext_vector_type(4))) float float4_t;
typedef __attribute__((ext_vector_type(4))) unsigned short ushort4_t;
typedef __attribute__((ext_vector_type(8))) unsigned short ushort8_t;

__device__ __forceinline__ unsigned short f2bf(float f) {
  uint32_t u = __builtin_bit_cast(uint32_t, f);
  u += 0x7fffu + ((u >> 16) & 1u);   // RNE
  return (unsigned short)(u >> 16);
}
__device__ __forceinline__ float bf2f(unsigned short h) {
  uint32_t u = ((uint32_t)h) << 16;
  return __builtin_bit_cast(float, u);
}

// async global->LDS, 16B per lane; LDS dest = wave-uniform base + lane*16
#define GLD16(gp, lp) __builtin_amdgcn_global_load_lds( \
    (const __attribute__((address_space(1))) void*)(gp), \
    (__attribute__((address_space(3))) void*)(lp), 16, 0, 0)

// ---------------------------------------------------------------- convert
__global__ __launch_bounds__(256) void cvt_kernel(
    const float* __restrict__ in, unsigned short* __restrict__ out, long n) {
  long i = ((long)blockIdx.x * 256 + threadIdx.x) * 8;
  if (i >= n) return;
  float4_t a = *(const float4_t*)(in + i);
  float4_t b = *(const float4_t*)(in + i + 4);
  ushort8_t r;
  r[0] = f2bf(a[0]); r[1] = f2bf(a[1]); r[2] = f2bf(a[2]); r[3] = f2bf(a[3]);
  r[4] = f2bf(b[0]); r[5] = f2bf(b[1]); r[6] = f2bf(b[2]); r[7] = f2bf(b[3]);
  *(ushort8_t*)(out + i) = r;
}

__global__ __launch_bounds__(256) void zero_f32(float* __restrict__ p) {
  int i = (blockIdx.x * 256 + threadIdx.x) * 4;
  *(float4_t*)(p + i) = (float4_t){0.f, 0.f, 0.f, 0.f};
}

// ---------------------------------------------------------------- GEMM C = A @ B^T
// A [M,K] bf16 row-major, B [N,K] bf16 row-major (K inner for both).
// 128x128 tile, BK=32, 4 waves (2x2), 16x16x32 bf16 MFMA, m97 2-barrier loop.
// MODE 0: epilogue scatters bf16 into Q [b,s,1024] / K,V [b,h,s,d] (+b_qkv)
// MODE 1: batched (blockIdx.z), fp32 out + b_proj
#define BM 128
#define BN 128
#define BK 32

template <int MODE>
__global__ __launch_bounds__(256, 2)
void gemm_bt(const unsigned short* __restrict__ Aall,
             const unsigned short* __restrict__ Ball,
             const float* __restrict__ bias,
             unsigned short* __restrict__ Oq,
             unsigned short* __restrict__ Ok,
             unsigned short* __restrict__ Ov,
             float* __restrict__ Of,
             int M, int Kdim)
{
  __shared__ __align__(16) unsigned short As[BM * BK];
  __shared__ __align__(16) unsigned short Bs[BN * BK];

  const int t = threadIdx.x;
  const int lane = t & 63;
  const int wid = t >> 6;
  const int wr = wid >> 1, wc = wid & 1;

  const int m0 = blockIdx.x * BM;
  const int n0 = blockIdx.y * BN;

  const unsigned short* A = Aall;
  const unsigned short* B = Ball;
  if (MODE == 1) {
    A += (size_t)blockIdx.z * M * Kdim;
    B += (size_t)blockIdx.z * DIM * Kdim;
  }

  // staging: unit u in [0,512): row=u>>2, 16B-seg = (u&3) XOR (row&3) on the
  // GLOBAL side (LDS dest stays linear -> rule #21 both-sides swizzle)
  const int r0 = t >> 2;
  const int r1 = r0 + 64;
  const int sseg = ((t & 3) ^ (r0 & 3)) * 8;          // elems
  const unsigned short* gA0 = A + (size_t)(m0 + r0) * Kdim + sseg;
  const unsigned short* gA1 = A + (size_t)(m0 + r1) * Kdim + sseg;
  const unsigned short* gB0 = B + (size_t)(n0 + r0) * Kdim + sseg;
  const unsigned short* gB1 = B + (size_t)(n0 + r1) * Kdim + sseg;

  char* lA0 = (char*)As + wid * 1024;
  char* lA1 = (char*)As + 4096 + wid * 1024;
  char* lB0 = (char*)Bs + wid * 1024;
  char* lB1 = (char*)Bs + 4096 + wid * 1024;

  // fragment read addresses (undo the seg swizzle: row&3 == lane&3 here)
  const int arow = wr * 64 + (lane & 15);
  const int brow = wc * 64 + (lane & 15);
  const int aoff = ((lane >> 4) ^ (lane & 3)) * 8;    // elems

  f32x4 acc[4][4];
#pragma unroll
  for (int i = 0; i < 4; ++i)
#pragma unroll
    for (int j = 0; j < 4; ++j) acc[i][j] = (f32x4){0.f, 0.f, 0.f, 0.f};

  const int KT = Kdim / BK;
  for (int kt = 0; kt < KT; ++kt) {
    GLD16(gA0, lA0); GLD16(gA1, lA1);
    GLD16(gB0, lB0); GLD16(gB1, lB1);
    gA0 += BK; gA1 += BK; gB0 += BK; gB1 += BK;
    __syncthreads();                       // drains vmcnt -> LDS tile ready
    bf16x8 af[4], bfr[4];
#pragma unroll
    for (int i = 0; i < 4; ++i)
      af[i] = *(const bf16x8*)(As + (arow + i * 16) * BK + aoff);
#pragma unroll
    for (int j = 0; j < 4; ++j)
      bfr[j] = *(const bf16x8*)(Bs + (brow + j * 16) * BK + aoff);
#pragma unroll
    for (int i = 0; i < 4; ++i)
#pragma unroll
      for (int j = 0; j < 4; ++j)
        acc[i][j] = __builtin_amdgcn_mfma_f32_16x16x32_bf16(af[i], bfr[j], acc[i][j], 0, 0, 0);
    __syncthreads();                       // protect LDS before next stage
  }

  // epilogue. C/D layout (m89-verified): col = lane&15, row = (lane>>4)*4 + reg
#pragma unroll
  for (int i = 0; i < 4; ++i) {
    const int rowb = m0 + wr * 64 + i * 16 + (lane >> 4) * 4;
#pragma unroll
    for (int j = 0; j < 4; ++j) {
      const int col = n0 + wc * 64 + j * 16 + (lane & 15);
      const float bv = bias[col];
#pragma unroll
      for (int r = 0; r < 4; ++r) {
        const float val = acc[i][j][r] + bv;
        const int rr = rowb + r;
        if (MODE == 0) {
          const unsigned short obf = f2bf(val);
          const int b = rr >> 12, s = rr & 4095;
          if (col < DIM) {
            Oq[(size_t)rr * DIM + col] = obf;               // Q [b,s,1024]
          } else if (col < 2 * DIM) {
            const int n2 = col - DIM;
            Ok[(((size_t)(b * NH + (n2 >> 6))) * SEQ + s) * HD + (n2 & 63)] = obf;
          } else {
            const int n2 = col - 2 * DIM;
            Ov[(((size_t)(b * NH + (n2 >> 6))) * SEQ + s) * HD + (n2 & 63)] = obf;
          }
        } else {
          Of[(size_t)blockIdx.z * M * DIM + (size_t)rr * DIM + col] = val;
        }
      }
    }
  }
}

// ------------------------------------------- column stats of K over seqlen
// grid (64 bh, 4 chunks of 1024 rows), block 256. Online max/sumexp.
__global__ __launch_bounds__(256)
void colstats_part(const unsigned short* __restrict__ Kb,
                   float* __restrict__ mpart, float* __restrict__ zpart)
{
  const int bh = blockIdx.x, ch = blockIdx.y;
  const int t = threadIdx.x;
  const int dp = t & 31;      // column pair d = 2*dp, 2*dp+1
  const int sr = t >> 5;      // 8 row phases
  const unsigned short* base = Kb + ((size_t)bh * SEQ + (size_t)ch * 1024) * HD;
  float mm[2] = {-1e30f, -1e30f}, zz[2] = {0.f, 0.f};
  for (int s = sr; s < 1024; s += 8) {
    uint32_t u = *(const uint32_t*)(base + (size_t)s * HD + dp * 2);
    float x[2] = {bf2f((unsigned short)(u & 0xffff)), bf2f((unsigned short)(u >> 16))};
#pragma unroll
    for (int c = 0; c < 2; ++c) {
      if (x[c] > mm[c]) { zz[c] = zz[c] * __expf(mm[c] - x[c]) + 1.f; mm[c] = x[c]; }
      else zz[c] += __expf(x[c] - mm[c]);
    }
  }
  __shared__ float sm[256][2], sz[256][2];
  sm[t][0] = mm[0]; sm[t][1] = mm[1]; sz[t][0] = zz[0]; sz[t][1] = zz[1];
  __syncthreads();
  if (t < 32) {
    for (int i = t + 32; i < 256; i += 32) {
#pragma unroll
      for (int c = 0; c < 2; ++c) {
        float m2 = sm[i][c], z2 = sz[i][c];
        if (m2 > mm[c]) { zz[c] = zz[c] * __expf(mm[c] - m2) + z2; mm[c] = m2; }
        else zz[c] += z2 * __expf(m2 - mm[c]);
      }
    }
    size_t o = ((size_t)bh * 4 + ch) * 64 + dp * 2;
    mpart[o] = mm[0]; mpart[o + 1] = mm[1];
    zpart[o] = zz[0]; zpart[o + 1] = zz[1];
  }
}

__global__ __launch_bounds__(256)
void colstats_fin(const float* __restrict__ mpart, const float* __restrict__ zpart,
                  float* __restrict__ mcol, float* __restrict__ zcol)
{
  const int i = blockIdx.x * 256 + threadIdx.x;   // (bh,d) in [0,4096)
  if (i >= 4096) return;
  const int bh = i >> 6, d = i & 63;
  float m = -1e30f, z = 0.f;
  for (int c = 0; c < 4; ++c) {
    float m2 = mpart[((size_t)bh * 4 + c) * 64 + d];
    float z2 = zpart[((size_t)bh * 4 + c) * 64 + d];
    if (m2 > m) { z = z * __expf(m - m2) + z2; m = m2; }
    else z += z2 * __expf(m2 - m);
  }
  mcol[i] = m; zcol[i] = z;
}

// ------------------------------------------- kv_raw[d,e] = sum_s exp(K-m_d)*V
// grid (64 bh, 8 s-chunks of 512), block 256: thread owns (d = t>>2, 16 e's)
__global__ __launch_bounds__(256)
void kv_partial(const unsigned short* __restrict__ Kb, const unsigned short* __restrict__ Vb,
                const float* __restrict__ mcol, float* __restrict__ kvws)
{
  __shared__ float Kl[32][64];
  __shared__ float Vl[32][64];
  const int bh = blockIdx.x, ch = blockIdx.y;
  const int t = threadIdx.x;
  const int d = t >> 2, e0 = (t & 3) * 16;
  const float m = mcol[bh * 64 + d];
  float acc[16];
#pragma unroll
  for (int j = 0; j < 16; ++j) acc[j] = 0.f;
  const unsigned short* Kbase = Kb + ((size_t)bh * SEQ + (size_t)ch * 512) * HD;
  const unsigned short* Vbase = Vb + ((size_t)bh * SEQ + (size_t)ch * 512) * HD;
  const int r = t >> 3, c = (t & 7) * 8;
  for (int s0 = 0; s0 < 512; s0 += 32) {
    bf16x8 k8 = *(const bf16x8*)(Kbase + (size_t)(s0 + r) * HD + c);
    bf16x8 v8 = *(const bf16x8*)(Vbase + (size_t)(s0 + r) * HD + c);
#pragma unroll
    for (int j = 0; j < 8; ++j) {
      Kl[r][c + j] = bf2f((unsigned short)k8[j]);
      Vl[r][c + j] = bf2f((unsigned short)v8[j]);
    }
    __syncthreads();
#pragma unroll 4
    for (int s = 0; s < 32; ++s) {
      float p = __expf(Kl[s][d] - m);
#pragma unroll
      for (int j = 0; j < 16; ++j) acc[j] += p * Vl[s][e0 + j];
    }
    __syncthreads();
  }
  float* dst = kvws + ((size_t)bh * 64 + d) * 64 + e0;
#pragma unroll
  for (int j = 0; j < 16; ++j) atomicAdd(dst + j, acc[j]);
}

// ------------------------------------------- MbT[b][n][h*64+d] = scale/Z_d * sum_e kv*Wp
// grid (4 b, 16 h, 16 nblk), block 256: thread = (n = nb*64 + t>>2, 16 d's)
__global__ __launch_bounds__(256)
void mbt_kernel(const float* __restrict__ kvws, const float* __restrict__ zcol,
                const float* __restrict__ wproj, unsigned short* __restrict__ MbT)
{
  __shared__ float kvl[64][65];
  const int b = blockIdx.x, h = blockIdx.y, nb = blockIdx.z;
  const int t = threadIdx.x;
  const int bh = b * NH + h;
  for (int u = t; u < 4096; u += 256) {
    int d = u >> 6, e = u & 63;
    float inv = QSCALE / zcol[bh * 64 + d];
    kvl[d][e] = kvws[((size_t)bh * 64 + d) * 64 + e] * inv;
  }
  __syncthreads();
  const int n = nb * 64 + (t >> 2);
  const int dg = (t & 3) * 16;
  const float* wrow = wproj + (size_t)n * DIM + h * HD;
  float out[16];
#pragma unroll
  for (int i = 0; i < 16; ++i) out[i] = 0.f;
  for (int e = 0; e < 64; e += 4) {
    float4_t w4 = *(const float4_t*)(wrow + e);
#pragma unroll
    for (int i = 0; i < 16; ++i)
      out[i] += w4[0] * kvl[dg + i][e] + w4[1] * kvl[dg + i][e + 1]
              + w4[2] * kvl[dg + i][e + 2] + w4[3] * kvl[dg + i][e + 3];
  }
  unsigned short* o = MbT + ((size_t)b * DIM + n) * DIM + h * HD + dg;
  ushort8_t o0, o1;
#pragma unroll
  for (int i = 0; i < 8; ++i) { o0[i] = f2bf(out[i]); o1[i] = f2bf(out[i + 8]); }
  *(ushort8_t*)(o) = o0;
  *(ushort8_t*)(o + 8) = o1;
}

// ------------------------------------------- in-place softmax of Q over head_dim
// wave handles 256 elems (4 heads); 16-lane-group shuffle reduce
__global__ __launch_bounds__(256)
void softmax_q(unsigned short* __restrict__ Q)
{
  const int t = threadIdx.x;
  const int lane = t & 63, wid = t >> 6;
  const size_t base = (((size_t)blockIdx.x * 4 + wid) * 256) + (size_t)lane * 4;
  ushort4_t q4 = *(const ushort4_t*)(Q + base);
  float x0 = bf2f(q4[0]), x1 = bf2f(q4[1]), x2 = bf2f(q4[2]), x3 = bf2f(q4[3]);
  float mx = fmaxf(fmaxf(x0, x1), fmaxf(x2, x3));
  for (int off = 1; off < 16; off <<= 1) mx = fmaxf(mx, __shfl_xor(mx, off, 16));
  float e0 = __expf(x0 - mx), e1 = __expf(x1 - mx);
  float e2 = __expf(x2 - mx), e3 = __expf(x3 - mx);
  float s = e0 + e1 + e2 + e3;
  for (int off = 1; off < 16; off <<= 1) s += __shfl_xor(s, off, 16);
  const float inv = 1.f / s;
  ushort4_t rr;
  rr[0] = f2bf(e0 * inv); rr[1] = f2bf(e1 * inv);
  rr[2] = f2bf(e2 * inv); rr[3] = f2bf(e3 * inv);
  *(ushort4_t*)(Q + base) = rr;
}

// ---------------------------------------------------------------- launch
extern "C" void kernel_launch(void* const* d_in, const int* in_sizes, int n_in,
                              void* d_out, int out_size, void* d_ws, size_t ws_size,
                              hipStream_t stream)
{
  const float* x      = (const float*)d_in[0];
  const float* w_qkv  = (const float*)d_in[1];
  const float* b_qkv  = (const float*)d_in[2];
  const float* w_proj = (const float*)d_in[3];
  const float* b_proj = (const float*)d_in[4];
  float* out = (float*)d_out;

  char* ws = (char*)d_ws;
  size_t off = 0;
  auto alloc = [&](size_t bytes) -> void* {
    void* p = ws + off;
    off += (bytes + 255) & ~(size_t)255;
    return p;
  };
  unsigned short* xb   = (unsigned short*)alloc(2ull * MTOT * DIM);   // 32 MB
  unsigned short* wqb  = (unsigned short*)alloc(2ull * NQKV * DIM);   //  6 MB
  unsigned short* Qb   = (unsigned short*)alloc(2ull * MTOT * DIM);   // 32 MB (P in-place later)
  unsigned short* Kb   = (unsigned short*)alloc(2ull * MTOT * DIM);   // 32 MB
  unsigned short* Vb   = (unsigned short*)alloc(2ull * MTOT * DIM);   // 32 MB
  float* mpart = (float*)alloc(4ull * 64 * 4 * 64);
  float* zpart = (float*)alloc(4ull * 64 * 4 * 64);
  float* mcol  = (float*)alloc(4ull * 4096);
  float* zcol  = (float*)alloc(4ull * 4096);
  float* kvws  = (float*)alloc(4ull * 64 * 64 * 64);                  //  1 MB
  unsigned short* MbT = (unsigned short*)alloc(2ull * BSZ * DIM * DIM); // 8 MB
  if (off > ws_size) return;   // insufficient workspace -> visible as incorrect

  cvt_kernel<<<8192, 256, 0, stream>>>(x, xb, (long)MTOT * DIM);
  cvt_kernel<<<1536, 256, 0, stream>>>(w_qkv, wqb, (long)NQKV * DIM);

  gemm_bt<0><<<dim3(128, 24), 256, 0, stream>>>(xb, wqb, b_qkv, Qb, Kb, Vb,
                                                nullptr, MTOT, DIM);

  colstats_part<<<dim3(64, 4), 256, 0, stream>>>(Kb, mpart, zpart);
  colstats_fin<<<16, 256, 0, stream>>>(mpart, zpart, mcol, zcol);

  zero_f32<<<256, 256, 0, stream>>>(kvws);
  kv_partial<<<dim3(64, 8), 256, 0, stream>>>(Kb, Vb, mcol, kvws);
  mbt_kernel<<<dim3(4, 16, 16), 256, 0, stream>>>(kvws, zcol, w_proj, MbT);

  softmax_q<<<16384, 256, 0, stream>>>(Qb);   // Qb becomes P (bf16)

  gemm_bt<1><<<dim3(32, 8, 4), 256, 0, stream>>>(Qb, MbT, b_proj,
                                                 nullptr, nullptr, nullptr, out,
                                                 SEQ, DIM);
}

// Round 2
// 408.611 us; speedup vs baseline: 1.4025x; 1.4025x over previous
//
#include <hip/hip_runtime.h>
#include <hip/hip_bf16.h>
#include <stdint.h>

// Linear-attention block: qkv proj -> (softmax_d q)*(scale), softmax_s k,
// kv = k^T v, out = q@kv, proj. Folded: MbT[b] = (kv/Z*scale) @ Wp^T so the
// final result is ONE batched GEMM: out[b] = P[b] @ MbT[b]^T + b_proj.
// K,V are produced TRANSPOSED ([bh][d][s]) by the qkv GEMM epilogue so that
// colstats is a row-reduce and kv = expK^T @ V runs on MFMA with
// s-contiguous fragments.

#define DIM 1024
#define NH 16
#define HD 64
#define BSZ 4
#define SEQ 4096
#define MTOT (BSZ*SEQ)      // 16384
#define NQKV (3*DIM)        // 3072
#define QSCALE 0.125f       // HD^-0.5
#define LOG2E 1.4426950408889634f

typedef __attribute__((ext_vector_type(8))) short bf16x8;
typedef __attribute__((ext_vector_type(4))) float f32x4;
typedef __attribute__((ext_vector_type(4))) float float4_t;
typedef __attribute__((ext_vector_type(4))) unsigned short ushort4_t;
typedef __attribute__((ext_vector_type(8))) unsigned short ushort8_t;

__device__ __forceinline__ unsigned short f2bf(float f) {
  uint32_t u = __builtin_bit_cast(uint32_t, f);
  u += 0x7fffu + ((u >> 16) & 1u);   // RNE
  return (unsigned short)(u >> 16);
}
__device__ __forceinline__ float bf2f(unsigned short h) {
  uint32_t u = ((uint32_t)h) << 16;
  return __builtin_bit_cast(float, u);
}

// async global->LDS, 16B per lane; LDS dest = wave-uniform base + lane*16
#define GLD16(gp, lp) __builtin_amdgcn_global_load_lds( \
    (const __attribute__((address_space(1))) void*)(gp), \
    (__attribute__((address_space(3))) void*)(lp), 16, 0, 0)

// ---------------------------------------------------------------- convert
__global__ __launch_bounds__(256) void cvt_kernel(
    const float* __restrict__ in, unsigned short* __restrict__ out, long n) {
  long i = ((long)blockIdx.x * 256 + threadIdx.x) * 8;
  if (i >= n) return;
  float4_t a = *(const float4_t*)(in + i);
  float4_t b = *(const float4_t*)(in + i + 4);
  ushort8_t r;
  r[0] = f2bf(a[0]); r[1] = f2bf(a[1]); r[2] = f2bf(a[2]); r[3] = f2bf(a[3]);
  r[4] = f2bf(b[0]); r[5] = f2bf(b[1]); r[6] = f2bf(b[2]); r[7] = f2bf(b[3]);
  *(ushort8_t*)(out + i) = r;
}

__global__ __launch_bounds__(256) void zero_f32(float* __restrict__ p) {
  int i = (blockIdx.x * 256 + threadIdx.x) * 4;
  *(float4_t*)(p + i) = (float4_t){0.f, 0.f, 0.f, 0.f};
}

// ---------------------------------------------------------------- GEMM C = A @ B^T
// A [M,K] bf16 row-major, B [N,K] bf16 row-major (K inner for both).
// 128x128 tile, BK=32, 4 waves (2x2), 16x16x32 bf16 MFMA, m97 2-barrier loop.
// MODE 0: epilogue scatters bf16: Q [b,s,1024]; K,V TRANSPOSED [bh,d,s] (+b_qkv)
// MODE 1: batched (blockIdx.z), fp32 out + b_proj
#define BM 128
#define BN 128
#define BK 32

template <int MODE>
__global__ __launch_bounds__(256, 2)
void gemm_bt(const unsigned short* __restrict__ Aall,
             const unsigned short* __restrict__ Ball,
             const float* __restrict__ bias,
             unsigned short* __restrict__ Oq,
             unsigned short* __restrict__ Okt,
             unsigned short* __restrict__ Ovt,
             float* __restrict__ Of,
             int M, int Kdim)
{
  __shared__ __align__(16) unsigned short As[BM * BK];
  __shared__ __align__(16) unsigned short Bs[BN * BK];

  const int t = threadIdx.x;
  const int lane = t & 63;
  const int wid = t >> 6;
  const int wr = wid >> 1, wc = wid & 1;

  const int m0 = blockIdx.x * BM;
  const int n0 = blockIdx.y * BN;

  const unsigned short* A = Aall;
  const unsigned short* B = Ball;
  if (MODE == 1) {
    A += (size_t)blockIdx.z * M * Kdim;
    B += (size_t)blockIdx.z * DIM * Kdim;
  }

  // staging: unit u in [0,512): row=u>>2, 16B-seg = (u&3) XOR (row&3) on the
  // GLOBAL side (LDS dest stays linear -> rule #21 both-sides swizzle)
  const int r0 = t >> 2;
  const int r1 = r0 + 64;
  const int sseg = ((t & 3) ^ (r0 & 3)) * 8;          // elems
  const unsigned short* gA0 = A + (size_t)(m0 + r0) * Kdim + sseg;
  const unsigned short* gA1 = A + (size_t)(m0 + r1) * Kdim + sseg;
  const unsigned short* gB0 = B + (size_t)(n0 + r0) * Kdim + sseg;
  const unsigned short* gB1 = B + (size_t)(n0 + r1) * Kdim + sseg;

  char* lA0 = (char*)As + wid * 1024;
  char* lA1 = (char*)As + 4096 + wid * 1024;
  char* lB0 = (char*)Bs + wid * 1024;
  char* lB1 = (char*)Bs + 4096 + wid * 1024;

  // fragment read addresses (undo the seg swizzle: row&3 == lane&3 here)
  const int arow = wr * 64 + (lane & 15);
  const int brow = wc * 64 + (lane & 15);
  const int aoff = ((lane >> 4) ^ (lane & 3)) * 8;    // elems

  f32x4 acc[4][4];
#pragma unroll
  for (int i = 0; i < 4; ++i)
#pragma unroll
    for (int j = 0; j < 4; ++j) acc[i][j] = (f32x4){0.f, 0.f, 0.f, 0.f};

  const int KT = Kdim / BK;
  for (int kt = 0; kt < KT; ++kt) {
    GLD16(gA0, lA0); GLD16(gA1, lA1);
    GLD16(gB0, lB0); GLD16(gB1, lB1);
    gA0 += BK; gA1 += BK; gB0 += BK; gB1 += BK;
    __syncthreads();                       // drains vmcnt -> LDS tile ready
    bf16x8 af[4], bfr[4];
#pragma unroll
    for (int i = 0; i < 4; ++i)
      af[i] = *(const bf16x8*)(As + (arow + i * 16) * BK + aoff);
#pragma unroll
    for (int j = 0; j < 4; ++j)
      bfr[j] = *(const bf16x8*)(Bs + (brow + j * 16) * BK + aoff);
#pragma unroll
    for (int i = 0; i < 4; ++i)
#pragma unroll
      for (int j = 0; j < 4; ++j)
        acc[i][j] = __builtin_amdgcn_mfma_f32_16x16x32_bf16(af[i], bfr[j], acc[i][j], 0, 0, 0);
    __syncthreads();                       // protect LDS before next stage
  }

  // epilogue. C/D layout (m89-verified): col = lane&15, row = (lane>>4)*4 + reg
#pragma unroll
  for (int i = 0; i < 4; ++i) {
    const int rowb = m0 + wr * 64 + i * 16 + (lane >> 4) * 4;
#pragma unroll
    for (int j = 0; j < 4; ++j) {
      const int col = n0 + wc * 64 + j * 16 + (lane & 15);
      const float bv = bias[col];
#pragma unroll
      for (int r = 0; r < 4; ++r) {
        const float val = acc[i][j][r] + bv;
        const int rr = rowb + r;
        if (MODE == 0) {
          const unsigned short obf = f2bf(val);
          const int b = rr >> 12, s = rr & 4095;
          if (col < DIM) {
            Oq[(size_t)rr * DIM + col] = obf;               // Q [b,s,1024]
          } else if (col < 2 * DIM) {
            const int n2 = col - DIM;
            const size_t bhd = (size_t)(b * NH + (n2 >> 6)) * HD + (n2 & 63);
            Okt[bhd * SEQ + s] = obf;                       // Kt [bh,d,s]
          } else {
            const int n2 = col - 2 * DIM;
            const size_t bhd = (size_t)(b * NH + (n2 >> 6)) * HD + (n2 & 63);
            Ovt[bhd * SEQ + s] = obf;                       // Vt [bh,e,s]
          }
        } else {
          Of[(size_t)blockIdx.z * M * DIM + (size_t)rr * DIM + col] = val;
        }
      }
    }
  }
}

// ------------------------------------------- row stats of Kt (max, sumexp over s)
// one wave per (bh,d) row of 4096 elems; 4 waves/block; grid 1024
__global__ __launch_bounds__(256)
void colstats_rows(const unsigned short* __restrict__ Kt,
                   float* __restrict__ mcol, float* __restrict__ zcol)
{
  const int row = blockIdx.x * 4 + (threadIdx.x >> 6);    // 0..4095
  const int lane = threadIdx.x & 63;
  const unsigned short* p = Kt + (size_t)row * SEQ + lane * 8;
  bf16x8 v[8];
#pragma unroll
  for (int c = 0; c < 8; ++c) v[c] = *(const bf16x8*)(p + c * 512);
  float mx = -1e30f;
#pragma unroll
  for (int c = 0; c < 8; ++c)
#pragma unroll
    for (int j = 0; j < 8; ++j) mx = fmaxf(mx, bf2f((unsigned short)v[c][j]));
#pragma unroll
  for (int off = 1; off < 64; off <<= 1) mx = fmaxf(mx, __shfl_xor(mx, off, 64));
  float s = 0.f;
#pragma unroll
  for (int c = 0; c < 8; ++c)
#pragma unroll
    for (int j = 0; j < 8; ++j) s += __expf(bf2f((unsigned short)v[c][j]) - mx);
#pragma unroll
  for (int off = 1; off < 64; off <<= 1) s += __shfl_xor(s, off, 64);
  if (lane == 0) { mcol[row] = mx; zcol[row] = s; }
}

// ------------------------------------------- kv_raw[d,e] += sum_s exp(Kt-m_d)*Vt
// MFMA: per block (bh, s-chunk of 512), 4 waves; wave w owns d-strip 16w..16w+15.
// LDS tiles [64 rows][128 s] bf16, source-swizzled: LDS chunk c holds global
// chunk c ^ (row&7)  (16B chunks) -> conflict-free ds_read_b128 fragments.
__global__ __launch_bounds__(256)
void kv_mfma(const unsigned short* __restrict__ Kt, const unsigned short* __restrict__ Vt,
             const float* __restrict__ mcol, float* __restrict__ kvws)
{
  __shared__ __align__(16) unsigned short Ks[64 * 128];
  __shared__ __align__(16) unsigned short Vs[64 * 128];
  const int bh = blockIdx.x, ch = blockIdx.y;
  const int t = threadIdx.x, lane = t & 63, w = t >> 6;
  const int r = lane & 15, g = lane >> 4;

  const float mc = mcol[bh * 64 + 16 * w + r] * LOG2E;   // for A-row d=16w+r
  const size_t kbase = (size_t)bh * 64 * SEQ;

  f32x4 acc[4];
#pragma unroll
  for (int j = 0; j < 4; ++j) acc[j] = (f32x4){0.f, 0.f, 0.f, 0.f};

  int s0 = ch * 512;
  for (int st = 0; st < 4; ++st, s0 += 128) {
    // stage: wave w stages its 16 rows of Ks and Vs (4 GLD16 each, 4 rows/instr)
#pragma unroll
    for (int q = 0; q < 4; ++q) {
      const int d = 16 * w + 4 * q + g;              // lane's source row
      const int gl = r ^ (d & 7);                    // swizzled global chunk
      const size_t go = kbase + (size_t)d * SEQ + s0 + gl * 8;
      GLD16(Kt + go, Ks + (16 * w + 4 * q) * 128);
      GLD16(Vt + go, Vs + (16 * w + 4 * q) * 128);
    }
    __syncthreads();                                 // drain vmcnt, tiles ready
#pragma unroll
    for (int ks = 0; ks < 4; ++ks) {
      const int coff = (((4 * ks + g) ^ (r & 7)) * 8);
      bf16x8 a = *(const bf16x8*)(Ks + (16 * w + r) * 128 + coff);
      bf16x8 ae;
#pragma unroll
      for (int j = 0; j < 8; ++j) {
        float f = bf2f((unsigned short)a[j]);
        float p = exp2f(f * LOG2E - mc);             // exp(k - m_d)
        ae[j] = (short)f2bf(p);
      }
#pragma unroll
      for (int jt = 0; jt < 4; ++jt) {
        bf16x8 b = *(const bf16x8*)(Vs + (16 * jt + r) * 128 + coff);
        acc[jt] = __builtin_amdgcn_mfma_f32_16x16x32_bf16(ae, b, acc[jt], 0, 0, 0);
      }
    }
    __syncthreads();
  }
  // C/D: col=lane&15 -> e=16jt+r ; row=g*4+reg -> d=16w+g*4+reg
#pragma unroll
  for (int jt = 0; jt < 4; ++jt)
#pragma unroll
    for (int reg = 0; reg < 4; ++reg)
      atomicAdd(&kvws[((size_t)bh * 64 + 16 * w + g * 4 + reg) * 64 + 16 * jt + r],
                acc[jt][reg]);
}

// ------------------------------------------- MbT[b][n][h*64+d] = scale/Z_d * sum_e kv*Wp
__global__ __launch_bounds__(256)
void mbt_kernel(const float* __restrict__ kvws, const float* __restrict__ zcol,
                const float* __restrict__ wproj, unsigned short* __restrict__ MbT)
{
  __shared__ float kvl[64][65];
  const int b = blockIdx.x, h = blockIdx.y, nb = blockIdx.z;
  const int t = threadIdx.x;
  const int bh = b * NH + h;
  for (int u = t; u < 4096; u += 256) {
    int d = u >> 6, e = u & 63;
    float inv = QSCALE / zcol[bh * 64 + d];
    kvl[d][e] = kvws[((size_t)bh * 64 + d) * 64 + e] * inv;
  }
  __syncthreads();
  const int n = nb * 64 + (t >> 2);
  const int dg = (t & 3) * 16;
  const float* wrow = wproj + (size_t)n * DIM + h * HD;
  float out[16];
#pragma unroll
  for (int i = 0; i < 16; ++i) out[i] = 0.f;
  for (int e = 0; e < 64; e += 4) {
    float4_t w4 = *(const float4_t*)(wrow + e);
#pragma unroll
    for (int i = 0; i < 16; ++i)
      out[i] += w4[0] * kvl[dg + i][e] + w4[1] * kvl[dg + i][e + 1]
              + w4[2] * kvl[dg + i][e + 2] + w4[3] * kvl[dg + i][e + 3];
  }
  unsigned short* o = MbT + ((size_t)b * DIM + n) * DIM + h * HD + dg;
  ushort8_t o0, o1;
#pragma unroll
  for (int i = 0; i < 8; ++i) { o0[i] = f2bf(out[i]); o1[i] = f2bf(out[i + 8]); }
  *(ushort8_t*)(o) = o0;
  *(ushort8_t*)(o + 8) = o1;
}

// ------------------------------------------- in-place softmax of Q over head_dim
__global__ __launch_bounds__(256)
void softmax_q(unsigned short* __restrict__ Q)
{
  const int t = threadIdx.x;
  const int lane = t & 63, wid = t >> 6;
  const size_t base = (((size_t)blockIdx.x * 4 + wid) * 256) + (size_t)lane * 4;
  ushort4_t q4 = *(const ushort4_t*)(Q + base);
  float x0 = bf2f(q4[0]), x1 = bf2f(q4[1]), x2 = bf2f(q4[2]), x3 = bf2f(q4[3]);
  float mx = fmaxf(fmaxf(x0, x1), fmaxf(x2, x3));
  for (int off = 1; off < 16; off <<= 1) mx = fmaxf(mx, __shfl_xor(mx, off, 16));
  float e0 = __expf(x0 - mx), e1 = __expf(x1 - mx);
  float e2 = __expf(x2 - mx), e3 = __expf(x3 - mx);
  float s = e0 + e1 + e2 + e3;
  for (int off = 1; off < 16; off <<= 1) s += __shfl_xor(s, off, 16);
  const float inv = 1.f / s;
  ushort4_t rr;
  rr[0] = f2bf(e0 * inv); rr[1] = f2bf(e1 * inv);
  rr[2] = f2bf(e2 * inv); rr[3] = f2bf(e3 * inv);
  *(ushort4_t*)(Q + base) = rr;
}

// ---------------------------------------------------------------- launch
extern "C" void kernel_launch(void* const* d_in, const int* in_sizes, int n_in,
                              void* d_out, int out_size, void* d_ws, size_t ws_size,
                              hipStream_t stream)
{
  const float* x      = (const float*)d_in[0];
  const float* w_qkv  = (const float*)d_in[1];
  const float* b_qkv  = (const float*)d_in[2];
  const float* w_proj = (const float*)d_in[3];
  const float* b_proj = (const float*)d_in[4];
  float* out = (float*)d_out;

  char* ws = (char*)d_ws;
  size_t off = 0;
  auto alloc = [&](size_t bytes) -> void* {
    void* p = ws + off;
    off += (bytes + 255) & ~(size_t)255;
    return p;
  };
  unsigned short* xb   = (unsigned short*)alloc(2ull * MTOT * DIM);   // 32 MB
  unsigned short* wqb  = (unsigned short*)alloc(2ull * NQKV * DIM);   //  6 MB
  unsigned short* Qb   = (unsigned short*)alloc(2ull * MTOT * DIM);   // 32 MB (P in-place later)
  unsigned short* Ktb  = (unsigned short*)alloc(2ull * MTOT * DIM);   // 32 MB [bh,d,s]
  unsigned short* Vtb  = (unsigned short*)alloc(2ull * MTOT * DIM);   // 32 MB [bh,e,s]
  float* mcol  = (float*)alloc(4ull * 4096);
  float* zcol  = (float*)alloc(4ull * 4096);
  float* kvws  = (float*)alloc(4ull * 64 * 64 * 64);                  //  1 MB
  unsigned short* MbT = (unsigned short*)alloc(2ull * BSZ * DIM * DIM); // 8 MB
  if (off > ws_size) return;   // insufficient workspace -> visible as incorrect

  cvt_kernel<<<8192, 256, 0, stream>>>(x, xb, (long)MTOT * DIM);
  cvt_kernel<<<1536, 256, 0, stream>>>(w_qkv, wqb, (long)NQKV * DIM);

  gemm_bt<0><<<dim3(128, 24), 256, 0, stream>>>(xb, wqb, b_qkv, Qb, Ktb, Vtb,
                                                nullptr, MTOT, DIM);

  colstats_rows<<<1024, 256, 0, stream>>>(Ktb, mcol, zcol);

  zero_f32<<<256, 256, 0, stream>>>(kvws);
  kv_mfma<<<dim3(64, 8), 256, 0, stream>>>(Ktb, Vtb, mcol, kvws);
  mbt_kernel<<<dim3(4, 16, 16), 256, 0, stream>>>(kvws, zcol, w_proj, MbT);

  softmax_q<<<16384, 256, 0, stream>>>(Qb);   // Qb becomes P (bf16)

  gemm_bt<1><<<dim3(32, 8, 4), 256, 0, stream>>>(Qb, MbT, b_proj,
                                                 nullptr, nullptr, nullptr, out,
                                                 SEQ, DIM);
}

// Round 4
// 403.394 us; speedup vs baseline: 1.4206x; 1.0129x over previous
//
#include <hip/hip_runtime.h>
#include <hip/hip_bf16.h>
#include <stdint.h>

// Linear-attention block: qkv proj -> (softmax_d q)*(scale), softmax_s k,
// kv = k^T v, out = q@kv, proj. Folded: MbT[b] = (kv/Z*scale) @ Wp^T so the
// final result is ONE batched GEMM: out[b] = P[b] @ MbT[b]^T + b_proj.
// Both big GEMMs use the 256x256 8-phase template (T2 swizzle + T3/T4
// counted-vmcnt pipeline + T5 setprio), K,V produced transposed [bh,d,s].

#define DIM 1024
#define NH 16
#define HD 64
#define BSZ 4
#define SEQ 4096
#define MTOT (BSZ*SEQ)      // 16384
#define NQKV (3*DIM)        // 3072
#define QSCALE 0.125f       // HD^-0.5
#define LOG2E 1.4426950408889634f

typedef __attribute__((ext_vector_type(8))) short bf16x8;
typedef __attribute__((ext_vector_type(4))) float f32x4;
typedef __attribute__((ext_vector_type(4))) float float4_t;
typedef __attribute__((ext_vector_type(4))) unsigned short ushort4_t;
typedef __attribute__((ext_vector_type(8))) unsigned short ushort8_t;

__device__ __forceinline__ unsigned short f2bf(float f) {
  uint32_t u = __builtin_bit_cast(uint32_t, f);
  u += 0x7fffu + ((u >> 16) & 1u);   // RNE
  return (unsigned short)(u >> 16);
}
__device__ __forceinline__ float bf2f(unsigned short h) {
  uint32_t u = ((uint32_t)h) << 16;
  return __builtin_bit_cast(float, u);
}

// async global->LDS, 16B per lane; LDS dest = wave-uniform base + lane*16
#define GLD16(gp, lp) __builtin_amdgcn_global_load_lds( \
    (const __attribute__((address_space(1))) void*)(gp), \
    (__attribute__((address_space(3))) void*)(lp), 16, 0, 0)

// ---------------------------------------------------------------- convert
__global__ __launch_bounds__(256) void cvt_kernel(
    const float* __restrict__ in, unsigned short* __restrict__ out, long n) {
  long i = ((long)blockIdx.x * 256 + threadIdx.x) * 8;
  if (i >= n) return;
  float4_t a = *(const float4_t*)(in + i);
  float4_t b = *(const float4_t*)(in + i + 4);
  ushort8_t r;
  r[0] = f2bf(a[0]); r[1] = f2bf(a[1]); r[2] = f2bf(a[2]); r[3] = f2bf(a[3]);
  r[4] = f2bf(b[0]); r[5] = f2bf(b[1]); r[6] = f2bf(b[2]); r[7] = f2bf(b[3]);
  *(ushort8_t*)(out + i) = r;
}

__global__ __launch_bounds__(256) void zero_f32(float* __restrict__ p) {
  int i = (blockIdx.x * 256 + threadIdx.x) * 4;
  *(float4_t*)(p + i) = (float4_t){0.f, 0.f, 0.f, 0.f};
}

// ------------------------------------------------- 256x256 8-phase GEMM, C = A @ B^T
// A [M,K] bf16 rm, B [N,K] bf16 rm. BK=64, 8 waves (2M x 4N), per-wave out 128x64
// (rows interleaved: row = 32*rep + 16*wm). LDS 128KB: 2 buf x (A 32KB + B 32KB),
// XOR chunk-swizzle (chunk ^= row&7) applied on GLOBAL source, LDS linear.
// Schedule: tile T staged at abs phases 4T-7..4T-4 (Bh0,Bh1,Ah0,Ah1), computed
// at 4T..4T+3; vmcnt(6) gate before each tile's compute (3 half-tiles=6 loads
// outstanding). MODE 0: scatter Q/Kt/Vt bf16 +bias. MODE 1: batched fp32 +bias.

#define LDA_(TB, MREP, KS) (*(const bf16x8*)(lds + (TB)*65536 + \
    (32*(MREP) + 16*wm + r4)*128 + ((((KS)*4 + g) ^ (r4 & 7))*16)))
#define LDB_(TB, NREP, KS) (*(const bf16x8*)(lds + (TB)*65536 + 32768 + \
    (wn*64 + (NREP)*16 + r4)*128 + ((((KS)*4 + g) ^ (r4 & 7))*16)))

#define STAGE(SB, ISB, H, KT_) do { \
    const unsigned short* _src = (ISB) ? B : A; \
    const int _rb = ((ISB) ? n0 : m0) + (H) * 128; \
    const unsigned short* _g0 = _src + (size_t)(_rb + srow) * Kdim + (KT_) * 64 + scol; \
    const unsigned short* _g1 = _src + (size_t)(_rb + 64 + srow) * Kdim + (KT_) * 64 + scol; \
    char* _l0 = lds + (SB) * 65536 + (ISB) * 32768 + (H) * 16384 + soff; \
    GLD16(_g0, _l0); \
    GLD16(_g1, _l0 + 8192); \
  } while (0)

#define MFMA_ __builtin_amdgcn_mfma_f32_16x16x32_bf16

#define PHASE(TB, P, LOADB, SB, SISB, SH, SKT, GATE) do { \
    if (LOADB) { \
      b00 = LDB_(TB,0,0); b01 = LDB_(TB,0,1); b10 = LDB_(TB,1,0); b11 = LDB_(TB,1,1); \
      b20 = LDB_(TB,2,0); b21 = LDB_(TB,2,1); b30 = LDB_(TB,3,0); b31 = LDB_(TB,3,1); \
    } \
    bf16x8 a00 = LDA_(TB,2*(P),0),   a01 = LDA_(TB,2*(P),1); \
    bf16x8 a10 = LDA_(TB,2*(P)+1,0), a11 = LDA_(TB,2*(P)+1,1); \
    STAGE(SB, SISB, SH, SKT); \
    __builtin_amdgcn_sched_barrier(0); \
    __builtin_amdgcn_s_barrier(); \
    asm volatile("s_waitcnt lgkmcnt(0)" ::: "memory"); \
    __builtin_amdgcn_sched_barrier(0); \
    __builtin_amdgcn_s_setprio(1); \
    acc[2*(P)][0]   = MFMA_(a00,b00,acc[2*(P)][0],0,0,0);   acc[2*(P)][0]   = MFMA_(a01,b01,acc[2*(P)][0],0,0,0); \
    acc[2*(P)][1]   = MFMA_(a00,b10,acc[2*(P)][1],0,0,0);   acc[2*(P)][1]   = MFMA_(a01,b11,acc[2*(P)][1],0,0,0); \
    acc[2*(P)][2]   = MFMA_(a00,b20,acc[2*(P)][2],0,0,0);   acc[2*(P)][2]   = MFMA_(a01,b21,acc[2*(P)][2],0,0,0); \
    acc[2*(P)][3]   = MFMA_(a00,b30,acc[2*(P)][3],0,0,0);   acc[2*(P)][3]   = MFMA_(a01,b31,acc[2*(P)][3],0,0,0); \
    acc[2*(P)+1][0] = MFMA_(a10,b00,acc[2*(P)+1][0],0,0,0); acc[2*(P)+1][0] = MFMA_(a11,b01,acc[2*(P)+1][0],0,0,0); \
    acc[2*(P)+1][1] = MFMA_(a10,b10,acc[2*(P)+1][1],0,0,0); acc[2*(P)+1][1] = MFMA_(a11,b11,acc[2*(P)+1][1],0,0,0); \
    acc[2*(P)+1][2] = MFMA_(a10,b20,acc[2*(P)+1][2],0,0,0); acc[2*(P)+1][2] = MFMA_(a11,b21,acc[2*(P)+1][2],0,0,0); \
    acc[2*(P)+1][3] = MFMA_(a10,b30,acc[2*(P)+1][3],0,0,0); acc[2*(P)+1][3] = MFMA_(a11,b31,acc[2*(P)+1][3],0,0,0); \
    __builtin_amdgcn_s_setprio(0); \
    __builtin_amdgcn_sched_barrier(0); \
    if (GATE) { asm volatile("s_waitcnt vmcnt(6)" ::: "memory"); } \
    __builtin_amdgcn_s_barrier(); \
    __builtin_amdgcn_sched_barrier(0); \
  } while (0)

template <int MODE>
__global__ __launch_bounds__(512, 2)
void gemm8p(const unsigned short* __restrict__ Aall,
            const unsigned short* __restrict__ Ball,
            const float* __restrict__ bias,
            unsigned short* __restrict__ Oq,
            unsigned short* __restrict__ Okt,
            unsigned short* __restrict__ Ovt,
            float* __restrict__ Of,
            int M, int Kdim)
{
  __shared__ __align__(16) char lds[131072];
  const int t = threadIdx.x, l = t & 63, wid = t >> 6;
  const int wm = wid >> 2, wn = wid & 3;
  const int r4 = l & 15, g = l >> 4;

  int bx, by;
  if (MODE == 0) {               // XCD swizzle (nwg = 768, 768%8==0 -> bijective)
    const int bid = blockIdx.y * gridDim.x + blockIdx.x;
    const int cpx = (gridDim.x * gridDim.y) >> 3;
    const int swz = (bid & 7) * cpx + (bid >> 3);
    bx = swz % gridDim.x;
    by = swz / gridDim.x;
  } else {
    bx = blockIdx.x; by = blockIdx.y;
  }
  const int m0 = bx * 256, n0 = by * 256;

  const unsigned short* A = Aall;
  const unsigned short* B = Ball;
  if (MODE == 1) {
    A += (size_t)blockIdx.z * M * Kdim;
    B += (size_t)blockIdx.z * DIM * Kdim;
  }

  // staging constants: thread covers (row = half*128 + q*64 + srow, chunk l&7);
  // global chunk fetched = (l&7) ^ (l>>3) = chunk ^ (row&7)  [inverse swizzle]
  // LDS dest is wave-uniform (HW adds lane*16): row wid*8+(l>>3), chunk l&7.
  const int srow = wid * 8 + (l >> 3);
  const int scol = ((l & 7) ^ (l >> 3)) * 8;     // elems
  const int soff = wid * 1024;                   // LDS bytes, wave-uniform

  f32x4 acc[8][4];
#pragma unroll
  for (int i = 0; i < 8; ++i)
#pragma unroll
    for (int j = 0; j < 4; ++j) acc[i][j] = (f32x4){0.f, 0.f, 0.f, 0.f};
  bf16x8 b00, b01, b10, b11, b20, b21, b30, b31;

  // prologue: tile0 fully (8 loads), then tile1's Bh0,Bh1,Ah0 (6 loads)
  STAGE(0, 1, 0, 0); STAGE(0, 1, 1, 0); STAGE(0, 0, 0, 0); STAGE(0, 0, 1, 0);
  STAGE(1, 1, 0, 1); STAGE(1, 1, 1, 1); STAGE(1, 0, 0, 1);
  asm volatile("s_waitcnt vmcnt(6)" ::: "memory");
  __builtin_amdgcn_sched_barrier(0);
  __builtin_amdgcn_s_barrier();
  __builtin_amdgcn_sched_barrier(0);

  const int KT = Kdim >> 6;
  for (int it = 0; it < (KT >> 1); ++it) {
    const int t1 = 2 * it + 1;
    int t2 = 2 * it + 2; if (t2 >= KT) t2 -= KT;   // tail: wrap (harmless restage)
    int t3 = 2 * it + 3; if (t3 >= KT) t3 -= KT;
    PHASE(0, 0, 1, 1, 0, 1, t1, 0);   // compute t0.p0 (load B), stage Ah1(t1)->buf1
    PHASE(0, 1, 0, 0, 1, 0, t2, 0);   // stage Bh0(t2)->buf0
    PHASE(0, 2, 0, 0, 1, 1, t2, 0);   // stage Bh1(t2)->buf0
    PHASE(0, 3, 0, 0, 0, 0, t2, 1);   // stage Ah0(t2)->buf0, GATE vmcnt(6)
    PHASE(1, 0, 1, 0, 0, 1, t2, 0);   // compute t1.p0 (load B), stage Ah1(t2)->buf0
    PHASE(1, 1, 0, 1, 1, 0, t3, 0);   // stage Bh0(t3)->buf1
    PHASE(1, 2, 0, 1, 1, 1, t3, 0);   // stage Bh1(t3)->buf1
    PHASE(1, 3, 0, 1, 0, 0, t3, 1);   // stage Ah0(t3)->buf1, GATE vmcnt(6)
  }

  // epilogue. C/D layout: out_row = m0+32*mrep+16*wm+g*4+reg, out_col = n0+wn*64+nrep*16+r4
  if (MODE == 0) {
    const int region = n0 >> 10;   // block-uniform: 0=Q, 1=K, 2=V
    float bv[4];
#pragma unroll
    for (int j = 0; j < 4; ++j) bv[j] = bias[n0 + wn * 64 + j * 16 + r4];
#pragma unroll
    for (int mi = 0; mi < 8; ++mi) {
      const int rowb = m0 + 32 * mi + 16 * wm + g * 4;
#pragma unroll
      for (int j = 0; j < 4; ++j) {
        const int col = n0 + wn * 64 + j * 16 + r4;
#pragma unroll
        for (int r = 0; r < 4; ++r) {
          const float val = acc[mi][j][r] + bv[j];
          const int rr = rowb + r;
          const unsigned short obf = f2bf(val);
          if (region == 0) {
            Oq[(size_t)rr * DIM + col] = obf;                  // Q [b,s,1024]
          } else {
            const int n2 = col - region * DIM;
            const int b = rr >> 12, s = rr & 4095;
            const size_t bhd = (size_t)(b * NH + (n2 >> 6)) * HD + (n2 & 63);
            if (region == 1) Okt[bhd * SEQ + s] = obf;         // Kt [bh,d,s]
            else             Ovt[bhd * SEQ + s] = obf;         // Vt [bh,e,s]
          }
        }
      }
    }
  } else {
    float* Ob = Of + (size_t)blockIdx.z * M * DIM;
#pragma unroll
    for (int mi = 0; mi < 8; ++mi) {
      const int rowb = m0 + 32 * mi + 16 * wm + g * 4;
#pragma unroll
      for (int j = 0; j < 4; ++j) {
        const int col = n0 + wn * 64 + j * 16 + r4;
        const float bvj = bias[col];
#pragma unroll
        for (int r = 0; r < 4; ++r)
          Ob[(size_t)(rowb + r) * DIM + col] = acc[mi][j][r] + bvj;
      }
    }
  }
}

// ------------------------------------------- row stats of Kt (max, sumexp over s)
__global__ __launch_bounds__(256)
void colstats_rows(const unsigned short* __restrict__ Kt,
                   float* __restrict__ mcol, float* __restrict__ zcol)
{
  const int row = blockIdx.x * 4 + (threadIdx.x >> 6);    // 0..4095
  const int lane = threadIdx.x & 63;
  const unsigned short* p = Kt + (size_t)row * SEQ + lane * 8;
  bf16x8 v[8];
#pragma unroll
  for (int c = 0; c < 8; ++c) v[c] = *(const bf16x8*)(p + c * 512);
  float mx = -1e30f;
#pragma unroll
  for (int c = 0; c < 8; ++c)
#pragma unroll
    for (int j = 0; j < 8; ++j) mx = fmaxf(mx, bf2f((unsigned short)v[c][j]));
#pragma unroll
  for (int off = 1; off < 64; off <<= 1) mx = fmaxf(mx, __shfl_xor(mx, off, 64));
  float s = 0.f;
#pragma unroll
  for (int c = 0; c < 8; ++c)
#pragma unroll
    for (int j = 0; j < 8; ++j) s += __expf(bf2f((unsigned short)v[c][j]) - mx);
#pragma unroll
  for (int off = 1; off < 64; off <<= 1) s += __shfl_xor(s, off, 64);
  if (lane == 0) { mcol[row] = mx; zcol[row] = s; }
}

// ------------------------------------------- kv_raw[d,e] += sum_s exp(Kt-m_d)*Vt
__global__ __launch_bounds__(256)
void kv_mfma(const unsigned short* __restrict__ Kt, const unsigned short* __restrict__ Vt,
             const float* __restrict__ mcol, float* __restrict__ kvws)
{
  __shared__ __align__(16) unsigned short Ks[64 * 128];
  __shared__ __align__(16) unsigned short Vs[64 * 128];
  const int bh = blockIdx.x, ch = blockIdx.y;
  const int t = threadIdx.x, lane = t & 63, w = t >> 6;
  const int r = lane & 15, g = lane >> 4;

  const float mc = mcol[bh * 64 + 16 * w + r] * LOG2E;   // for A-row d=16w+r
  const size_t kbase = (size_t)bh * 64 * SEQ;

  f32x4 acc[4];
#pragma unroll
  for (int j = 0; j < 4; ++j) acc[j] = (f32x4){0.f, 0.f, 0.f, 0.f};

  int s0 = ch * 512;
  for (int st = 0; st < 4; ++st, s0 += 128) {
#pragma unroll
    for (int q = 0; q < 4; ++q) {
      const int d = 16 * w + 4 * q + g;              // lane's source row
      const int gl = r ^ (d & 7);                    // swizzled global chunk
      const size_t go = kbase + (size_t)d * SEQ + s0 + gl * 8;
      GLD16(Kt + go, Ks + (16 * w + 4 * q) * 128);
      GLD16(Vt + go, Vs + (16 * w + 4 * q) * 128);
    }
    __syncthreads();                                 // drain vmcnt, tiles ready
#pragma unroll
    for (int ks = 0; ks < 4; ++ks) {
      const int coff = (((4 * ks + g) ^ (r & 7)) * 8);
      bf16x8 a = *(const bf16x8*)(Ks + (16 * w + r) * 128 + coff);
      bf16x8 ae;
#pragma unroll
      for (int j = 0; j < 8; ++j) {
        float f = bf2f((unsigned short)a[j]);
        float p = exp2f(f * LOG2E - mc);             // exp(k - m_d)
        ae[j] = (short)f2bf(p);
      }
#pragma unroll
      for (int jt = 0; jt < 4; ++jt) {
        bf16x8 b = *(const bf16x8*)(Vs + (16 * jt + r) * 128 + coff);
        acc[jt] = __builtin_amdgcn_mfma_f32_16x16x32_bf16(ae, b, acc[jt], 0, 0, 0);
      }
    }
    __syncthreads();
  }
#pragma unroll
  for (int jt = 0; jt < 4; ++jt)
#pragma unroll
    for (int reg = 0; reg < 4; ++reg)
      atomicAdd(&kvws[((size_t)bh * 64 + 16 * w + g * 4 + reg) * 64 + 16 * jt + r],
                acc[jt][reg]);
}

// ------------------------------------------- MbT[b][n][h*64+d] = scale/Z_d * sum_e kv*Wp
__global__ __launch_bounds__(256)
void mbt_kernel(const float* __restrict__ kvws, const float* __restrict__ zcol,
                const float* __restrict__ wproj, unsigned short* __restrict__ MbT)
{
  __shared__ float kvl[64][65];
  const int b = blockIdx.x, h = blockIdx.y, nb = blockIdx.z;
  const int t = threadIdx.x;
  const int bh = b * NH + h;
  for (int u = t; u < 4096; u += 256) {
    int d = u >> 6, e = u & 63;
    float inv = QSCALE / zcol[bh * 64 + d];
    kvl[d][e] = kvws[((size_t)bh * 64 + d) * 64 + e] * inv;
  }
  __syncthreads();
  const int n = nb * 64 + (t >> 2);
  const int dg = (t & 3) * 16;
  const float* wrow = wproj + (size_t)n * DIM + h * HD;
  float out[16];
#pragma unroll
  for (int i = 0; i < 16; ++i) out[i] = 0.f;
  for (int e = 0; e < 64; e += 4) {
    float4_t w4 = *(const float4_t*)(wrow + e);
#pragma unroll
    for (int i = 0; i < 16; ++i)
      out[i] += w4[0] * kvl[dg + i][e] + w4[1] * kvl[dg + i][e + 1]
              + w4[2] * kvl[dg + i][e + 2] + w4[3] * kvl[dg + i][e + 3];
  }
  unsigned short* o = MbT + ((size_t)b * DIM + n) * DIM + h * HD + dg;
  ushort8_t o0, o1;
#pragma unroll
  for (int i = 0; i < 8; ++i) { o0[i] = f2bf(out[i]); o1[i] = f2bf(out[i + 8]); }
  *(ushort8_t*)(o) = o0;
  *(ushort8_t*)(o + 8) = o1;
}

// ------------------------------------------- in-place softmax of Q over head_dim
__global__ __launch_bounds__(256)
void softmax_q(unsigned short* __restrict__ Q)
{
  const int t = threadIdx.x;
  const int lane = t & 63, wid = t >> 6;
  const size_t base = (((size_t)blockIdx.x * 4 + wid) * 256) + (size_t)lane * 4;
  ushort4_t q4 = *(const ushort4_t*)(Q + base);
  float x0 = bf2f(q4[0]), x1 = bf2f(q4[1]), x2 = bf2f(q4[2]), x3 = bf2f(q4[3]);
  float mx = fmaxf(fmaxf(x0, x1), fmaxf(x2, x3));
  for (int off = 1; off < 16; off <<= 1) mx = fmaxf(mx, __shfl_xor(mx, off, 16));
  float e0 = __expf(x0 - mx), e1 = __expf(x1 - mx);
  float e2 = __expf(x2 - mx), e3 = __expf(x3 - mx);
  float s = e0 + e1 + e2 + e3;
  for (int off = 1; off < 16; off <<= 1) s += __shfl_xor(s, off, 16);
  const float inv = 1.f / s;
  ushort4_t rr;
  rr[0] = f2bf(e0 * inv); rr[1] = f2bf(e1 * inv);
  rr[2] = f2bf(e2 * inv); rr[3] = f2bf(e3 * inv);
  *(ushort4_t*)(Q + base) = rr;
}

// ---------------------------------------------------------------- launch
extern "C" void kernel_launch(void* const* d_in, const int* in_sizes, int n_in,
                              void* d_out, int out_size, void* d_ws, size_t ws_size,
                              hipStream_t stream)
{
  const float* x      = (const float*)d_in[0];
  const float* w_qkv  = (const float*)d_in[1];
  const float* b_qkv  = (const float*)d_in[2];
  const float* w_proj = (const float*)d_in[3];
  const float* b_proj = (const float*)d_in[4];
  float* out = (float*)d_out;

  char* ws = (char*)d_ws;
  size_t off = 0;
  auto alloc = [&](size_t bytes) -> void* {
    void* p = ws + off;
    off += (bytes + 255) & ~(size_t)255;
    return p;
  };
  unsigned short* xb   = (unsigned short*)alloc(2ull * MTOT * DIM);   // 32 MB
  unsigned short* wqb  = (unsigned short*)alloc(2ull * NQKV * DIM);   //  6 MB
  unsigned short* Qb   = (unsigned short*)alloc(2ull * MTOT * DIM);   // 32 MB (P in-place later)
  unsigned short* Ktb  = (unsigned short*)alloc(2ull * MTOT * DIM);   // 32 MB [bh,d,s]
  unsigned short* Vtb  = (unsigned short*)alloc(2ull * MTOT * DIM);   // 32 MB [bh,e,s]
  float* mcol  = (float*)alloc(4ull * 4096);
  float* zcol  = (float*)alloc(4ull * 4096);
  float* kvws  = (float*)alloc(4ull * 64 * 64 * 64);                  //  1 MB
  unsigned short* MbT = (unsigned short*)alloc(2ull * BSZ * DIM * DIM); // 8 MB
  if (off > ws_size) return;   // insufficient workspace -> visible as incorrect

  cvt_kernel<<<8192, 256, 0, stream>>>(x, xb, (long)MTOT * DIM);
  cvt_kernel<<<1536, 256, 0, stream>>>(w_qkv, wqb, (long)NQKV * DIM);

  gemm8p<0><<<dim3(64, 12), 512, 0, stream>>>(xb, wqb, b_qkv, Qb, Ktb, Vtb,
                                              nullptr, MTOT, DIM);

  colstats_rows<<<1024, 256, 0, stream>>>(Ktb, mcol, zcol);

  zero_f32<<<256, 256, 0, stream>>>(kvws);
  kv_mfma<<<dim3(64, 8), 256, 0, stream>>>(Ktb, Vtb, mcol, kvws);
  mbt_kernel<<<dim3(4, 16, 16), 256, 0, stream>>>(kvws, zcol, w_proj, MbT);

  softmax_q<<<16384, 256, 0, stream>>>(Qb);   // Qb becomes P (bf16)

  gemm8p<1><<<dim3(16, 4, 4), 512, 0, stream>>>(Qb, MbT, b_proj,
                                                nullptr, nullptr, nullptr, out,
                                                SEQ, DIM);
}

// Round 5
// 368.989 us; speedup vs baseline: 1.5531x; 1.0932x over previous
//
#include <hip/hip_runtime.h>
#include <hip/hip_bf16.h>
#include <stdint.h>

// Linear-attention block: qkv proj -> (softmax_d q)*(scale), softmax_s k,
// kv = k^T v, out = q@kv, proj. Folded: MbT[b] = (kv/Z*scale) @ Wp^T so the
// final result is ONE batched GEMM: out[b] = P[b] @ MbT[b]^T + b_proj.
// gemm8p writes ONE coalesced QKVb [16384][3072]; a dedicated in-register
// transpose kernel produces Kt/Vt [bh,d,s]; kv = expK^T @ V runs on MFMA.

#define DIM 1024
#define NH 16
#define HD 64
#define BSZ 4
#define SEQ 4096
#define MTOT (BSZ*SEQ)      // 16384
#define NQKV (3*DIM)        // 3072
#define QSCALE 0.125f       // HD^-0.5
#define LOG2E 1.4426950408889634f

typedef __attribute__((ext_vector_type(8))) short bf16x8;
typedef __attribute__((ext_vector_type(4))) float f32x4;
typedef __attribute__((ext_vector_type(4))) float float4_t;
typedef __attribute__((ext_vector_type(4))) unsigned short ushort4_t;
typedef __attribute__((ext_vector_type(8))) unsigned short ushort8_t;

__device__ __forceinline__ unsigned short f2bf(float f) {
  uint32_t u = __builtin_bit_cast(uint32_t, f);
  u += 0x7fffu + ((u >> 16) & 1u);   // RNE
  return (unsigned short)(u >> 16);
}
__device__ __forceinline__ float bf2f(unsigned short h) {
  uint32_t u = ((uint32_t)h) << 16;
  return __builtin_bit_cast(float, u);
}

// async global->LDS, 16B per lane; LDS dest = wave-uniform base + lane*16
#define GLD16(gp, lp) __builtin_amdgcn_global_load_lds( \
    (const __attribute__((address_space(1))) void*)(gp), \
    (__attribute__((address_space(3))) void*)(lp), 16, 0, 0)

// ---------------------------------------------------------------- convert
__global__ __launch_bounds__(256) void cvt_kernel(
    const float* __restrict__ in, unsigned short* __restrict__ out, long n) {
  long i = ((long)blockIdx.x * 256 + threadIdx.x) * 8;
  if (i >= n) return;
  float4_t a = *(const float4_t*)(in + i);
  float4_t b = *(const float4_t*)(in + i + 4);
  ushort8_t r;
  r[0] = f2bf(a[0]); r[1] = f2bf(a[1]); r[2] = f2bf(a[2]); r[3] = f2bf(a[3]);
  r[4] = f2bf(b[0]); r[5] = f2bf(b[1]); r[6] = f2bf(b[2]); r[7] = f2bf(b[3]);
  *(ushort8_t*)(out + i) = r;
}

__global__ __launch_bounds__(256) void zero_f32(float* __restrict__ p) {
  int i = (blockIdx.x * 256 + threadIdx.x) * 4;
  *(float4_t*)(p + i) = (float4_t){0.f, 0.f, 0.f, 0.f};
}

// ------------------------------------------------- 256x256 8-phase GEMM, C = A @ B^T
// A [M,*lda] bf16 rm, B [N,*ldb] bf16 rm, K = Kdim. BK=64, 8 waves (2M x 4N),
// per-wave out 128x64 (rows interleaved: row = 32*rep + 16*wm). LDS 128KB:
// 2 buf x (A 32KB + B 32KB), XOR chunk-swizzle on GLOBAL source, LDS linear.
// Tile T staged at abs phases 4T-7..4T-4 (Bh0,Bh1,Ah0,Ah1), computed at
// 4T..4T+3; vmcnt(6) gate per tile. MODE 0: bf16 out (QKVb, stride ldo) +bias.
// MODE 1: batched fp32 out +bias.

#define LDA_(TB, MREP, KS) (*(const bf16x8*)(lds + (TB)*65536 + \
    (32*(MREP) + 16*wm + r4)*128 + ((((KS)*4 + g) ^ (r4 & 7))*16)))
#define LDB_(TB, NREP, KS) (*(const bf16x8*)(lds + (TB)*65536 + 32768 + \
    (wn*64 + (NREP)*16 + r4)*128 + ((((KS)*4 + g) ^ (r4 & 7))*16)))

#define STAGE(SB, ISB, H, KT_) do { \
    const unsigned short* _src = (ISB) ? B : A; \
    const int _ld = (ISB) ? ldb : lda; \
    const int _rb = ((ISB) ? n0 : m0) + (H) * 128; \
    const unsigned short* _g0 = _src + (size_t)(_rb + srow) * _ld + (KT_) * 64 + scol; \
    const unsigned short* _g1 = _src + (size_t)(_rb + 64 + srow) * _ld + (KT_) * 64 + scol; \
    char* _l0 = lds + (SB) * 65536 + (ISB) * 32768 + (H) * 16384 + soff; \
    GLD16(_g0, _l0); \
    GLD16(_g1, _l0 + 8192); \
  } while (0)

#define MFMA_ __builtin_amdgcn_mfma_f32_16x16x32_bf16

#define PHASE(TB, P, LOADB, SB, SISB, SH, SKT, GATE) do { \
    if (LOADB) { \
      b00 = LDB_(TB,0,0); b01 = LDB_(TB,0,1); b10 = LDB_(TB,1,0); b11 = LDB_(TB,1,1); \
      b20 = LDB_(TB,2,0); b21 = LDB_(TB,2,1); b30 = LDB_(TB,3,0); b31 = LDB_(TB,3,1); \
    } \
    bf16x8 a00 = LDA_(TB,2*(P),0),   a01 = LDA_(TB,2*(P),1); \
    bf16x8 a10 = LDA_(TB,2*(P)+1,0), a11 = LDA_(TB,2*(P)+1,1); \
    STAGE(SB, SISB, SH, SKT); \
    __builtin_amdgcn_sched_barrier(0); \
    __builtin_amdgcn_s_barrier(); \
    asm volatile("s_waitcnt lgkmcnt(0)" ::: "memory"); \
    __builtin_amdgcn_sched_barrier(0); \
    __builtin_amdgcn_s_setprio(1); \
    acc[2*(P)][0]   = MFMA_(a00,b00,acc[2*(P)][0],0,0,0);   acc[2*(P)][0]   = MFMA_(a01,b01,acc[2*(P)][0],0,0,0); \
    acc[2*(P)][1]   = MFMA_(a00,b10,acc[2*(P)][1],0,0,0);   acc[2*(P)][1]   = MFMA_(a01,b11,acc[2*(P)][1],0,0,0); \
    acc[2*(P)][2]   = MFMA_(a00,b20,acc[2*(P)][2],0,0,0);   acc[2*(P)][2]   = MFMA_(a01,b21,acc[2*(P)][2],0,0,0); \
    acc[2*(P)][3]   = MFMA_(a00,b30,acc[2*(P)][3],0,0,0);   acc[2*(P)][3]   = MFMA_(a01,b31,acc[2*(P)][3],0,0,0); \
    acc[2*(P)+1][0] = MFMA_(a10,b00,acc[2*(P)+1][0],0,0,0); acc[2*(P)+1][0] = MFMA_(a11,b01,acc[2*(P)+1][0],0,0,0); \
    acc[2*(P)+1][1] = MFMA_(a10,b10,acc[2*(P)+1][1],0,0,0); acc[2*(P)+1][1] = MFMA_(a11,b11,acc[2*(P)+1][1],0,0,0); \
    acc[2*(P)+1][2] = MFMA_(a10,b20,acc[2*(P)+1][2],0,0,0); acc[2*(P)+1][2] = MFMA_(a11,b21,acc[2*(P)+1][2],0,0,0); \
    acc[2*(P)+1][3] = MFMA_(a10,b30,acc[2*(P)+1][3],0,0,0); acc[2*(P)+1][3] = MFMA_(a11,b31,acc[2*(P)+1][3],0,0,0); \
    __builtin_amdgcn_s_setprio(0); \
    __builtin_amdgcn_sched_barrier(0); \
    if (GATE) { asm volatile("s_waitcnt vmcnt(6)" ::: "memory"); } \
    __builtin_amdgcn_s_barrier(); \
    __builtin_amdgcn_sched_barrier(0); \
  } while (0)

template <int MODE>
__global__ __launch_bounds__(512, 2)
void gemm8p(const unsigned short* __restrict__ Aall,
            const unsigned short* __restrict__ Ball,
            const float* __restrict__ bias,
            unsigned short* __restrict__ Obf,
            float* __restrict__ Of,
            int M, int Kdim, int lda, int ldb, int ldo)
{
  __shared__ __align__(16) char lds[131072];
  const int t = threadIdx.x, l = t & 63, wid = t >> 6;
  const int wm = wid >> 2, wn = wid & 3;
  const int r4 = l & 15, g = l >> 4;

  int bx, by;
  if (MODE == 0) {               // XCD swizzle (nwg = 768, 768%8==0 -> bijective)
    const int bid = blockIdx.y * gridDim.x + blockIdx.x;
    const int cpx = (gridDim.x * gridDim.y) >> 3;
    const int swz = (bid & 7) * cpx + (bid >> 3);
    bx = swz % gridDim.x;
    by = swz / gridDim.x;
  } else {
    bx = blockIdx.x; by = blockIdx.y;
  }
  const int m0 = bx * 256, n0 = by * 256;

  const unsigned short* A = Aall;
  const unsigned short* B = Ball;
  if (MODE == 1) {
    A += (size_t)blockIdx.z * M * lda;
    B += (size_t)blockIdx.z * DIM * ldb;
  }

  // staging: thread covers (row = half*128 + wid*8 + l>>3, chunk l&7);
  // global chunk fetched = (l&7) ^ (l>>3) = chunk ^ (row&7) [inverse swizzle];
  // LDS dest wave-uniform (HW adds lane*16)
  const int srow = wid * 8 + (l >> 3);
  const int scol = ((l & 7) ^ (l >> 3)) * 8;     // elems
  const int soff = wid * 1024;                   // LDS bytes, wave-uniform

  f32x4 acc[8][4];
#pragma unroll
  for (int i = 0; i < 8; ++i)
#pragma unroll
    for (int j = 0; j < 4; ++j) acc[i][j] = (f32x4){0.f, 0.f, 0.f, 0.f};
  bf16x8 b00, b01, b10, b11, b20, b21, b30, b31;

  // prologue: tile0 fully (8 loads), then tile1's Bh0,Bh1,Ah0 (6 loads)
  STAGE(0, 1, 0, 0); STAGE(0, 1, 1, 0); STAGE(0, 0, 0, 0); STAGE(0, 0, 1, 0);
  STAGE(1, 1, 0, 1); STAGE(1, 1, 1, 1); STAGE(1, 0, 0, 1);
  asm volatile("s_waitcnt vmcnt(6)" ::: "memory");
  __builtin_amdgcn_sched_barrier(0);
  __builtin_amdgcn_s_barrier();
  __builtin_amdgcn_sched_barrier(0);

  const int KT = Kdim >> 6;
  for (int it = 0; it < (KT >> 1); ++it) {
    const int t1 = 2 * it + 1;
    int t2 = 2 * it + 2; if (t2 >= KT) t2 -= KT;   // tail: wrap (harmless restage)
    int t3 = 2 * it + 3; if (t3 >= KT) t3 -= KT;
    PHASE(0, 0, 1, 1, 0, 1, t1, 0);   // compute t0.p0 (load B), stage Ah1(t1)->buf1
    PHASE(0, 1, 0, 0, 1, 0, t2, 0);   // stage Bh0(t2)->buf0
    PHASE(0, 2, 0, 0, 1, 1, t2, 0);   // stage Bh1(t2)->buf0
    PHASE(0, 3, 0, 0, 0, 0, t2, 1);   // stage Ah0(t2)->buf0, GATE vmcnt(6)
    PHASE(1, 0, 1, 0, 0, 1, t2, 0);   // compute t1.p0 (load B), stage Ah1(t2)->buf0
    PHASE(1, 1, 0, 1, 1, 0, t3, 0);   // stage Bh0(t3)->buf1
    PHASE(1, 2, 0, 1, 1, 1, t3, 0);   // stage Bh1(t3)->buf1
    PHASE(1, 3, 0, 1, 0, 0, t3, 1);   // stage Ah0(t3)->buf1, GATE vmcnt(6)
  }

  // epilogue. C/D: out_row = m0+32*mi+16*wm+4g+r, out_col = n0+wn*64+j*16+r4.
  // j-inner store order -> adjacent 32B runs merge in L2.
  if (MODE == 0) {
    float bv[4];
#pragma unroll
    for (int j = 0; j < 4; ++j) bv[j] = bias[n0 + wn * 64 + j * 16 + r4];
#pragma unroll
    for (int mi = 0; mi < 8; ++mi) {
      const int rowb = m0 + 32 * mi + 16 * wm + g * 4;
#pragma unroll
      for (int r = 0; r < 4; ++r) {
        unsigned short* orow = Obf + (size_t)(rowb + r) * ldo + n0 + wn * 64 + r4;
#pragma unroll
        for (int j = 0; j < 4; ++j)
          orow[j * 16] = f2bf(acc[mi][j][r] + bv[j]);
      }
    }
  } else {
    float* Ob = Of + (size_t)blockIdx.z * M * ldo;
#pragma unroll
    for (int mi = 0; mi < 8; ++mi) {
      const int rowb = m0 + 32 * mi + 16 * wm + g * 4;
#pragma unroll
      for (int r = 0; r < 4; ++r) {
        float* orow = Ob + (size_t)(rowb + r) * ldo + n0 + wn * 64 + r4;
#pragma unroll
        for (int j = 0; j < 4; ++j)
          orow[j * 16] = acc[mi][j][r] + bias[n0 + wn * 64 + j * 16 + r4];
      }
    }
  }
}

// ------------------------------------------- in-register transpose K,V -> Kt,Vt
// grid (64 bh, 32 s-chunks of 128, 2 K/V), block 256 (4 waves, wave = 64d x 32s).
// Lane loads 8 rows x 4 cols (uint2, coalesced 128B runs), repacks in-lane,
// stores bf16x8; lanes {l,l+16,l+32,l+48} of one instr cover a full 64B line.
__global__ __launch_bounds__(256)
void transpose_kv(const unsigned short* __restrict__ QKVb,
                  unsigned short* __restrict__ Kt,
                  unsigned short* __restrict__ Vt)
{
  const int bh = blockIdx.x;
  const int S0 = blockIdx.y * 128;
  unsigned short* dst = (blockIdx.z == 0) ? Kt : Vt;
  const int c0 = (1 + blockIdx.z) * 1024 + (bh & 15) * 64;
  const int t = threadIdx.x, l = t & 63, w = t >> 6;
  const int d0 = (l & 15) * 4;
  const int sg = (l >> 4) * 8;
  const size_t R0 = (size_t)(bh >> 4) * SEQ + S0 + w * 32 + sg;

  uint32_t lo[8], hi[8];
#pragma unroll
  for (int j = 0; j < 8; ++j) {
    uint2 v = *(const uint2*)(QKVb + (R0 + j) * NQKV + c0 + d0);
    lo[j] = v.x; hi[j] = v.y;
  }
  ushort8_t o0, o1, o2, o3;
#pragma unroll
  for (int j = 0; j < 8; ++j) {
    o0[j] = (unsigned short)(lo[j] & 0xffff);
    o1[j] = (unsigned short)(lo[j] >> 16);
    o2[j] = (unsigned short)(hi[j] & 0xffff);
    o3[j] = (unsigned short)(hi[j] >> 16);
  }
  const size_t obase = ((size_t)bh * 64 + d0) * SEQ + S0 + w * 32 + sg;
  *(ushort8_t*)(dst + obase)           = o0;
  *(ushort8_t*)(dst + obase + SEQ)     = o1;
  *(ushort8_t*)(dst + obase + 2 * SEQ) = o2;
  *(ushort8_t*)(dst + obase + 3 * SEQ) = o3;
}

// ------------------------------------------- row stats of Kt (max, sumexp over s)
__global__ __launch_bounds__(256)
void colstats_rows(const unsigned short* __restrict__ Kt,
                   float* __restrict__ mcol, float* __restrict__ zcol)
{
  const int row = blockIdx.x * 4 + (threadIdx.x >> 6);    // 0..4095
  const int lane = threadIdx.x & 63;
  const unsigned short* p = Kt + (size_t)row * SEQ + lane * 8;
  bf16x8 v[8];
#pragma unroll
  for (int c = 0; c < 8; ++c) v[c] = *(const bf16x8*)(p + c * 512);
  float mx = -1e30f;
#pragma unroll
  for (int c = 0; c < 8; ++c)
#pragma unroll
    for (int j = 0; j < 8; ++j) mx = fmaxf(mx, bf2f((unsigned short)v[c][j]));
#pragma unroll
  for (int off = 1; off < 64; off <<= 1) mx = fmaxf(mx, __shfl_xor(mx, off, 64));
  float s = 0.f;
#pragma unroll
  for (int c = 0; c < 8; ++c)
#pragma unroll
    for (int j = 0; j < 8; ++j) s += __expf(bf2f((unsigned short)v[c][j]) - mx);
#pragma unroll
  for (int off = 1; off < 64; off <<= 1) s += __shfl_xor(s, off, 64);
  if (lane == 0) { mcol[row] = mx; zcol[row] = s; }
}

// ------------------------------------------- kv_raw[d,e] += sum_s exp(Kt-m_d)*Vt
__global__ __launch_bounds__(256)
void kv_mfma(const unsigned short* __restrict__ Kt, const unsigned short* __restrict__ Vt,
             const float* __restrict__ mcol, float* __restrict__ kvws)
{
  __shared__ __align__(16) unsigned short Ks[64 * 128];
  __shared__ __align__(16) unsigned short Vs[64 * 128];
  const int bh = blockIdx.x, ch = blockIdx.y;
  const int t = threadIdx.x, lane = t & 63, w = t >> 6;
  const int r = lane & 15, g = lane >> 4;

  const float mc = mcol[bh * 64 + 16 * w + r] * LOG2E;   // for A-row d=16w+r
  const size_t kbase = (size_t)bh * 64 * SEQ;

  f32x4 acc[4];
#pragma unroll
  for (int j = 0; j < 4; ++j) acc[j] = (f32x4){0.f, 0.f, 0.f, 0.f};

  int s0 = ch * 512;
  for (int st = 0; st < 4; ++st, s0 += 128) {
#pragma unroll
    for (int q = 0; q < 4; ++q) {
      const int d = 16 * w + 4 * q + g;              // lane's source row
      const int gl = r ^ (d & 7);                    // swizzled global chunk
      const size_t go = kbase + (size_t)d * SEQ + s0 + gl * 8;
      GLD16(Kt + go, Ks + (16 * w + 4 * q) * 128);
      GLD16(Vt + go, Vs + (16 * w + 4 * q) * 128);
    }
    __syncthreads();                                 // drain vmcnt, tiles ready
#pragma unroll
    for (int ks = 0; ks < 4; ++ks) {
      const int coff = (((4 * ks + g) ^ (r & 7)) * 8);
      bf16x8 a = *(const bf16x8*)(Ks + (16 * w + r) * 128 + coff);
      bf16x8 ae;
#pragma unroll
      for (int j = 0; j < 8; ++j) {
        float f = bf2f((unsigned short)a[j]);
        float p = exp2f(f * LOG2E - mc);             // exp(k - m_d)
        ae[j] = (short)f2bf(p);
      }
#pragma unroll
      for (int jt = 0; jt < 4; ++jt) {
        bf16x8 b = *(const bf16x8*)(Vs + (16 * jt + r) * 128 + coff);
        acc[jt] = __builtin_amdgcn_mfma_f32_16x16x32_bf16(ae, b, acc[jt], 0, 0, 0);
      }
    }
    __syncthreads();
  }
#pragma unroll
  for (int jt = 0; jt < 4; ++jt)
#pragma unroll
    for (int reg = 0; reg < 4; ++reg)
      atomicAdd(&kvws[((size_t)bh * 64 + 16 * w + g * 4 + reg) * 64 + 16 * jt + r],
                acc[jt][reg]);
}

// ------------------------------------------- MbT[b][n][h*64+d] = scale/Z_d * sum_e kv*Wp
__global__ __launch_bounds__(256)
void mbt_kernel(const float* __restrict__ kvws, const float* __restrict__ zcol,
                const float* __restrict__ wproj, unsigned short* __restrict__ MbT)
{
  __shared__ float kvl[64][65];
  const int b = blockIdx.x, h = blockIdx.y, nb = blockIdx.z;
  const int t = threadIdx.x;
  const int bh = b * NH + h;
  for (int u = t; u < 4096; u += 256) {
    int d = u >> 6, e = u & 63;
    float inv = QSCALE / zcol[bh * 64 + d];
    kvl[d][e] = kvws[((size_t)bh * 64 + d) * 64 + e] * inv;
  }
  __syncthreads();
  const int n = nb * 64 + (t >> 2);
  const int dg = (t & 3) * 16;
  const float* wrow = wproj + (size_t)n * DIM + h * HD;
  float out[16];
#pragma unroll
  for (int i = 0; i < 16; ++i) out[i] = 0.f;
  for (int e = 0; e < 64; e += 4) {
    float4_t w4 = *(const float4_t*)(wrow + e);
#pragma unroll
    for (int i = 0; i < 16; ++i)
      out[i] += w4[0] * kvl[dg + i][e] + w4[1] * kvl[dg + i][e + 1]
              + w4[2] * kvl[dg + i][e + 2] + w4[3] * kvl[dg + i][e + 3];
  }
  unsigned short* o = MbT + ((size_t)b * DIM + n) * DIM + h * HD + dg;
  ushort8_t o0, o1;
#pragma unroll
  for (int i = 0; i < 8; ++i) { o0[i] = f2bf(out[i]); o1[i] = f2bf(out[i + 8]); }
  *(ushort8_t*)(o) = o0;
  *(ushort8_t*)(o + 8) = o1;
}

// ------------------------------------------- in-place softmax of Q cols of QKVb
// grid 16384 (one row), 4 waves: wave w handles cols w*256..w*256+255 (4 heads)
__global__ __launch_bounds__(256)
void softmax_q(unsigned short* __restrict__ QKVb)
{
  const int t = threadIdx.x;
  const int lane = t & 63, wid = t >> 6;
  const size_t base = (size_t)blockIdx.x * NQKV + wid * 256 + lane * 4;
  ushort4_t q4 = *(const ushort4_t*)(QKVb + base);
  float x0 = bf2f(q4[0]), x1 = bf2f(q4[1]), x2 = bf2f(q4[2]), x3 = bf2f(q4[3]);
  float mx = fmaxf(fmaxf(x0, x1), fmaxf(x2, x3));
  for (int off = 1; off < 16; off <<= 1) mx = fmaxf(mx, __shfl_xor(mx, off, 16));
  float e0 = __expf(x0 - mx), e1 = __expf(x1 - mx);
  float e2 = __expf(x2 - mx), e3 = __expf(x3 - mx);
  float s = e0 + e1 + e2 + e3;
  for (int off = 1; off < 16; off <<= 1) s += __shfl_xor(s, off, 16);
  const float inv = 1.f / s;
  ushort4_t rr;
  rr[0] = f2bf(e0 * inv); rr[1] = f2bf(e1 * inv);
  rr[2] = f2bf(e2 * inv); rr[3] = f2bf(e3 * inv);
  *(ushort4_t*)(QKVb + base) = rr;
}

// ---------------------------------------------------------------- launch
extern "C" void kernel_launch(void* const* d_in, const int* in_sizes, int n_in,
                              void* d_out, int out_size, void* d_ws, size_t ws_size,
                              hipStream_t stream)
{
  const float* x      = (const float*)d_in[0];
  const float* w_qkv  = (const float*)d_in[1];
  const float* b_qkv  = (const float*)d_in[2];
  const float* w_proj = (const float*)d_in[3];
  const float* b_proj = (const float*)d_in[4];
  float* out = (float*)d_out;

  char* ws = (char*)d_ws;
  size_t off = 0;
  auto alloc = [&](size_t bytes) -> void* {
    void* p = ws + off;
    off += (bytes + 255) & ~(size_t)255;
    return p;
  };
  unsigned short* xb   = (unsigned short*)alloc(2ull * MTOT * DIM);    // 32 MB
  unsigned short* wqb  = (unsigned short*)alloc(2ull * NQKV * DIM);    //  6 MB
  unsigned short* QKVb = (unsigned short*)alloc(2ull * MTOT * NQKV);   // 96 MB
  unsigned short* Ktb  = (unsigned short*)alloc(2ull * MTOT * DIM);    // 32 MB [bh,d,s]
  float* mcol  = (float*)alloc(4ull * 4096);
  float* zcol  = (float*)alloc(4ull * 4096);
  float* kvws  = (float*)alloc(4ull * 64 * 64 * 64);                   //  1 MB
  unsigned short* MbT = (unsigned short*)alloc(2ull * BSZ * DIM * DIM); // 8 MB
  unsigned short* Vtb = xb;   // xb is dead after gemm8p<0> -> alias for Vt
  if (off > ws_size) return;  // insufficient workspace -> visible as incorrect

  cvt_kernel<<<8192, 256, 0, stream>>>(x, xb, (long)MTOT * DIM);
  cvt_kernel<<<1536, 256, 0, stream>>>(w_qkv, wqb, (long)NQKV * DIM);

  gemm8p<0><<<dim3(64, 12), 512, 0, stream>>>(xb, wqb, b_qkv, QKVb, nullptr,
                                              MTOT, DIM, DIM, DIM, NQKV);

  transpose_kv<<<dim3(64, 32, 2), 256, 0, stream>>>(QKVb, Ktb, Vtb);

  colstats_rows<<<1024, 256, 0, stream>>>(Ktb, mcol, zcol);

  zero_f32<<<256, 256, 0, stream>>>(kvws);
  kv_mfma<<<dim3(64, 8), 256, 0, stream>>>(Ktb, Vtb, mcol, kvws);
  mbt_kernel<<<dim3(4, 16, 16), 256, 0, stream>>>(kvws, zcol, w_proj, MbT);

  softmax_q<<<16384, 256, 0, stream>>>(QKVb);   // Q cols become P in-place

  gemm8p<1><<<dim3(16, 4, 4), 512, 0, stream>>>(QKVb, MbT, b_proj, nullptr, out,
                                                SEQ, DIM, NQKV, DIM, DIM);
}